// Round 3
// baseline (29606.491 us; speedup 1.0000x reference)
//
#include <hip/hip_runtime.h>
#include <hip/hip_bf16.h>
#include <math.h>

typedef __hip_bfloat16 bf16;

#define BB 16
#define TT 2048
#define DM 64
#define DI 128
#define DSN 16

__device__ __forceinline__ bf16  f2b(float v){ return __float2bfloat16(v); }
__device__ __forceinline__ float b2f(bf16 v){ return __bfloat162float(v); }
__device__ __forceinline__ float siluf(float x){ return x / (1.f + __expf(-x)); }
__device__ __forceinline__ float leakyf(float x){ return x >= 0.f ? x : 0.01f*x; }
__device__ __forceinline__ float softplusf(float x){ return x > 20.f ? x : log1pf(__expf(x)); }

__global__ __launch_bounds__(256) void k_zero(float* __restrict__ p, int n){
  int i = blockIdx.x*256 + threadIdx.x;
  if (i < n) p[i] = 0.f;
}

// ---------------- stage 1: conv_in (12->64, k=15, pad 7) + leaky; dual-layout out ----
__global__ __launch_bounds__(256) void k_conv_in(
    const float* __restrict__ x, const float* __restrict__ w,
    const float* __restrict__ bias, float* __restrict__ h, float* __restrict__ ht)
{
  __shared__ float sx[12][272];
  __shared__ float sw[12][15];
  int tid = threadIdx.x;
  int t0 = blockIdx.x * 256;
  int co = blockIdx.y;
  int b  = blockIdx.z;
  for (int i = tid; i < 12*15; i += 256) sw[i/15][i%15] = w[co*180 + i];
  for (int i = tid; i < 12*270; i += 256) {
    int ci = i/270, L = i%270;
    int tt = t0 - 7 + L;
    sx[ci][L] = (tt >= 0 && tt < TT) ? x[((size_t)b*12+ci)*TT + tt] : 0.f;
  }
  __syncthreads();
  float acc = bias[co];
  #pragma unroll
  for (int ci = 0; ci < 12; ci++) {
    #pragma unroll
    for (int k = 0; k < 15; k++)
      acc += sx[ci][tid+k]*sw[ci][k];
  }
  acc = leakyf(acc);
  int t = t0 + tid;
  h [((size_t)b*DM + co)*TT + t] = acc;
  ht[((size_t)b*TT + t)*DM + co] = acc;
}

// ---------------- stage 2a: rmsnorm + in_proj (64 -> 256), wave per (b,t) ----------
__global__ __launch_bounds__(256) void k_inproj(
    const float* __restrict__ ht, const float* __restrict__ nw,
    const float* __restrict__ w, float* __restrict__ xm, float* __restrict__ z)
{
  __shared__ float sxn[4][64];
  int lane = threadIdx.x & 63, wid = threadIdx.x >> 6;
  int bt = blockIdx.x*4 + wid;
  float v = ht[(size_t)bt*DM + lane];
  float ss = v*v;
  #pragma unroll
  for (int o = 32; o; o >>= 1) ss += __shfl_xor(ss, o);
  sxn[wid][lane] = v * rsqrtf(ss*(1.f/64.f) + 1e-5f) * nw[lane];
  __syncthreads();
  #pragma unroll
  for (int i = 0; i < 4; i++) {
    int j = i*64 + lane;
    const float* wr = w + (size_t)j*DM;
    float acc = 0.f;
    #pragma unroll
    for (int d = 0; d < 64; d++) acc += sxn[wid][d]*wr[d];
    if (j < DI) xm[(size_t)bt*DI + j] = acc;
    else        z [(size_t)bt*DI + (j-DI)] = acc;
  }
}

// ---------------- stage 2b: causal depthwise conv k=4 + silu ----------------------
__global__ __launch_bounds__(256) void k_dwconv(
    const float* __restrict__ xm, const float* __restrict__ w,
    const float* __restrict__ bias, float* __restrict__ xc)
{
  int idx = blockIdx.x*256 + threadIdx.x;        // (b*T+t)*DI + c
  int c = idx & (DI-1);
  int bt = idx / DI;
  int t = bt & (TT-1);
  float acc = bias[c];
  #pragma unroll
  for (int k = 0; k < 4; k++) {
    int tt = t - 3 + k;
    if (tt >= 0) acc += xm[(size_t)(bt - t + tt)*DI + c] * w[c*4+k];
  }
  xc[idx] = siluf(acc);
}

// ---------------- stage 2c: x_proj (128 -> 36) ------------------------------------
__global__ __launch_bounds__(256) void k_xproj(
    const float* __restrict__ xc, const float* __restrict__ w, float* __restrict__ xd)
{
  int idx = blockIdx.x*256 + threadIdx.x;        // bt*36 + j
  int j = idx % 36;
  int bt = idx / 36;
  const float* xr = xc + (size_t)bt*DI;
  const float* wr = w + (size_t)j*DI;
  float acc = 0.f;
  #pragma unroll
  for (int c = 0; c < DI; c++) acc += xr[c]*wr[c];
  xd[idx] = acc;
}

// ---------------- stage 2d: dt_proj + softplus ------------------------------------
__global__ __launch_bounds__(256) void k_delta(
    const float* __restrict__ xd, const float* __restrict__ w,
    const float* __restrict__ bias, float* __restrict__ dlt)
{
  int idx = blockIdx.x*256 + threadIdx.x;        // bt*DI + c
  int c = idx & (DI-1);
  int bt = idx / DI;
  const float* dt = xd + (size_t)bt*36;
  float acc = bias[c];
  #pragma unroll
  for (int r = 0; r < 4; r++) acc += dt[r]*w[c*4+r];
  dlt[idx] = softplusf(acc);
}

// ---------------- stage 2e: selective scan; thread = (b,d,n) ----------------------
__global__ __launch_bounds__(256) void k_scan(
    const float* __restrict__ dlt, const float* __restrict__ xc,
    const float* __restrict__ xd, const float* __restrict__ A_log,
    const float* __restrict__ Dv, float* __restrict__ y)
{
  int tid = threadIdx.x;
  int n  = tid & 15;
  int dl = tid >> 4;
  int d  = blockIdx.x*16 + dl;
  int b  = blockIdx.y;
  float A  = -__expf(A_log[d*DSN + n]);
  float Dd = Dv[d];
  float hst = 0.f;
  size_t base = (size_t)b*TT;
  float cd = dlt[base*DI + d];
  float cu = xc [base*DI + d];
  float cB = xd [base*36 + 4  + n];
  float cC = xd [base*36 + 20 + n];
  for (int t = 0; t < TT; t++) {
    int tn = (t+1 < TT) ? t+1 : t;
    size_t ib = base + tn;
    float nd = dlt[ib*DI + d];
    float nu = xc [ib*DI + d];
    float nB = xd [ib*36 + 4  + n];
    float nC = xd [ib*36 + 20 + n];
    float dA = __expf(cd*A);
    hst = hst*dA + cd*cu*cB;
    float c = hst*cC;
    c += __shfl_xor(c, 1); c += __shfl_xor(c, 2);
    c += __shfl_xor(c, 4); c += __shfl_xor(c, 8);
    if (n == 0) y[(base+t)*DI + d] = c + cu*Dd;
    cd = nd; cu = nu; cB = nB; cC = nC;
  }
}

// ---------------- stage 2f: gate + out_proj (128 -> 64) + residual ----------------
__global__ __launch_bounds__(256) void k_outproj(
    const float* __restrict__ y, const float* __restrict__ z,
    const float* __restrict__ ht, const float* __restrict__ w,
    float* __restrict__ s_out)
{
  __shared__ float sy[4][128];
  int lane = threadIdx.x & 63, wid = threadIdx.x >> 6;
  int bt = blockIdx.x*4 + wid;
  int b = bt / TT, t = bt & (TT-1);
  #pragma unroll
  for (int i = 0; i < 2; i++) {
    int c = i*64 + lane;
    float zz = z[(size_t)bt*DI + c];
    sy[wid][c] = y[(size_t)bt*DI + c] * siluf(zz);
  }
  __syncthreads();
  const float* wr = w + (size_t)lane*DI;
  float acc = ht[(size_t)bt*DM + lane];
  #pragma unroll
  for (int c = 0; c < DI; c++) acc += sy[wid][c]*wr[c];
  s_out[((size_t)b*DM + lane)*TT + t] = acc;
}

// ---------------- generic k=15 pad=7 conv, 4 outputs/thread, fused shuffle --------
// grid: (Cout, Tlen/1024, B); block 256. in layout (B, CIN, Tlen).
// out layout (B, Cout/R, Tlen*R), out[b][co/R][t*R + co%R].
template<int CIN, bool IN_BF16, bool OUT_BF16, bool LEAKY, bool STATS, int R>
__global__ __launch_bounds__(256) void conv15(
    const void* __restrict__ inv, const float* __restrict__ w,
    const float* __restrict__ bias, void* __restrict__ outv,
    float* __restrict__ stats, int Tlen, int Couts)
{
  constexpr int CH = 8;
  __shared__ __align__(16) float sx[CH][1040];
  __shared__ float sw[CH][15];
  __shared__ float red[8];
  const int tid = threadIdx.x;
  const int co   = blockIdx.x;
  const int t0   = blockIdx.y * 1024;
  const int b    = blockIdx.z;
  const float* inf = (const float*)inv;
  const bf16*  inb = (const bf16*)inv;
  float acc0=0.f, acc1=0.f, acc2=0.f, acc3=0.f;
  for (int cc = 0; cc < CIN/CH; cc++) {
    __syncthreads();
    for (int i = tid; i < CH*1040; i += 256) {
      int ci = i / 1040, L = i % 1040;
      int tt = t0 - 7 + L;
      float v = 0.f;
      if (tt >= 0 && tt < Tlen) {
        size_t idx = ((size_t)(b*CIN + cc*CH + ci))*Tlen + tt;
        v = IN_BF16 ? b2f(inb[idx]) : inf[idx];
      }
      sx[ci][L] = v;
    }
    if (tid < CH*15) sw[tid/15][tid%15] = w[((size_t)co*CIN + cc*CH + tid/15)*15 + tid%15];
    __syncthreads();
    #pragma unroll
    for (int ci = 0; ci < CH; ci++) {
      const float* row = sx[ci];
      float f[20];
      #pragma unroll
      for (int qi = 0; qi < 5; qi++) {
        float4 q = *(const float4*)&row[4*tid + 4*qi];
        f[4*qi]=q.x; f[4*qi+1]=q.y; f[4*qi+2]=q.z; f[4*qi+3]=q.w;
      }
      float wk[15];
      #pragma unroll
      for (int k = 0; k < 15; k++) wk[k] = sw[ci][k];
      #pragma unroll
      for (int k = 0; k < 15; k++) {
        acc0 += f[k  ]*wk[k];
        acc1 += f[k+1]*wk[k];
        acc2 += f[k+2]*wk[k];
        acc3 += f[k+3]*wk[k];
      }
    }
  }
  float bv = bias[co];
  float a[4] = {acc0+bv, acc1+bv, acc2+bv, acc3+bv};
  int t = t0 + 4*tid;
  size_t obase = ((size_t)(b*Couts + co/R))*((size_t)Tlen*R) + (size_t)t*R + (co % R);
  #pragma unroll
  for (int j = 0; j < 4; j++) {
    float v = a[j];
    if (LEAKY) v = leakyf(v);
    if (OUT_BF16) ((bf16*)outv)[obase + (size_t)j*R] = f2b(v);
    else          ((float*)outv)[obase + (size_t)j*R] = v;
  }
  if (STATS) {
    float s1 = a[0]+a[1]+a[2]+a[3];
    float s2 = a[0]*a[0]+a[1]*a[1]+a[2]*a[2]+a[3]*a[3];
    #pragma unroll
    for (int o = 32; o; o >>= 1) { s1 += __shfl_xor(s1,o); s2 += __shfl_xor(s2,o); }
    int lane = tid & 63, wv = tid >> 6;
    if (lane == 0) { red[wv] = s1; red[4+wv] = s2; }
    __syncthreads();
    if (tid == 0) {
      atomicAdd(&stats[co],        red[0]+red[1]+red[2]+red[3]);
      atomicAdd(&stats[Couts+co],  red[4]+red[5]+red[6]+red[7]);
    }
  }
}

// ---------------- BN apply + residual hold ----------------------------------------
__global__ __launch_bounds__(256) void k_bnadd(
    float* __restrict__ m, const float* __restrict__ stats,
    const float* __restrict__ g, const float* __restrict__ bb,
    const float* __restrict__ h)
{
  int idx = blockIdx.x*256 + threadIdx.x;     // (b*64+co)*T + t
  int co = (idx / TT) & (DM-1);
  const float cnt = (float)(BB*TT);
  float mu  = stats[co] / cnt;
  float var = stats[DM+co] / cnt - mu*mu;
  float inv = rsqrtf(var + 1e-5f);
  m[idx] = (m[idx]-mu)*inv*g[co] + bb[co] + h[idx];
}

// ==================================================================================
extern "C" void kernel_launch(void* const* d_in, const int* in_sizes, int n_in,
                              void* d_out, int out_size, void* d_ws, size_t ws_size,
                              hipStream_t stream)
{
  const float* in_x       = (const float*)d_in[0];
  const float* conv_in_w  = (const float*)d_in[1];
  const float* conv_in_b  = (const float*)d_in[2];
  const float* norm_w     = (const float*)d_in[3];
  const float* in_proj_w  = (const float*)d_in[4];
  const float* dwconv_w   = (const float*)d_in[5];
  const float* dwconv_b   = (const float*)d_in[6];
  const float* x_proj_w   = (const float*)d_in[7];
  const float* dt_proj_w  = (const float*)d_in[8];
  const float* dt_proj_b  = (const float*)d_in[9];
  const float* A_log      = (const float*)d_in[10];
  const float* Dvec       = (const float*)d_in[11];
  const float* out_proj_w = (const float*)d_in[12];
  const float* merge_w    = (const float*)d_in[13];
  const float* merge_b    = (const float*)d_in[14];
  const float* bn_g       = (const float*)d_in[15];
  const float* bn_b       = (const float*)d_in[16];
  const float* up1_w      = (const float*)d_in[17];
  const float* up1_b      = (const float*)d_in[18];
  const float* up2_w      = (const float*)d_in[19];
  const float* up2_b      = (const float*)d_in[20];
  const float* out_w      = (const float*)d_in[21];
  const float* out_b      = (const float*)d_in[22];
  float* out = (float*)d_out;   // reference output dtype is float32

  // ---- workspace layout (u10 overlaps dead mamba temps) ----
  size_t off = 0;
  auto take = [&](size_t bytes) -> void* {
    void* p = (char*)d_ws + off;
    off += (bytes + 255) & ~(size_t)255;
    return p;
  };
  const size_t F_BDMT = (size_t)BB*DM*TT;    // 2,097,152
  const size_t F_BTDI = (size_t)BB*TT*DI;    // 4,194,304
  const size_t F_XDBL = (size_t)BB*TT*36;
  float* g_h   = (float*)take(F_BDMT*4);
  float* g_ht  = (float*)take(F_BDMT*4);
  float* g_s   = (float*)take(F_BDMT*4);
  float* g_m   = (float*)take(F_BDMT*4);
  float* g_st  = (float*)take(512);
  size_t mamba_base = off;
  float* g_xm  = (float*)take(F_BTDI*4);
  float* g_z   = (float*)take(F_BTDI*4);
  float* g_xc  = (float*)take(F_BTDI*4);
  float* g_xd  = (float*)take(F_XDBL*4);
  float* g_dl  = (float*)take(F_BTDI*4);
  float* g_y   = (float*)take(F_BTDI*4);
  bf16*  g_u10 = (bf16*)((char*)d_ws + mamba_base);   // 80 MB, fits in mamba region (~88.6 MB)
  bf16*  g_u5  = (bf16*)take((size_t)BB*320*TT*5*2);  // 104.9 MB
  if (off > ws_size) return;  // workspace too small: leave output poisoned (visible failure)

  // ---- stage 1 ----
  k_zero<<<1, 256, 0, stream>>>(g_st, 128);
  k_conv_in<<<dim3(TT/256, DM, BB), 256, 0, stream>>>(in_x, conv_in_w, conv_in_b, g_h, g_ht);

  // ---- stage 2: mamba ----
  k_inproj <<<BB*TT/4, 256, 0, stream>>>(g_ht, norm_w, in_proj_w, g_xm, g_z);
  k_dwconv <<<BB*TT*DI/256, 256, 0, stream>>>(g_xm, dwconv_w, dwconv_b, g_xc);
  k_xproj  <<<BB*TT*36/256, 256, 0, stream>>>(g_xc, x_proj_w, g_xd);
  k_delta  <<<BB*TT*DI/256, 256, 0, stream>>>(g_xd, dt_proj_w, dt_proj_b, g_dl);
  k_scan   <<<dim3(DI/16, BB), 256, 0, stream>>>(g_dl, g_xc, g_xd, A_log, Dvec, g_y);
  k_outproj<<<BB*TT/4, 256, 0, stream>>>(g_y, g_z, g_ht, out_proj_w, g_s);

  // ---- stage 3: merge conv + BN + hold ----
  conv15<64,false,false,false,true,1><<<dim3(64, TT/1024, BB), 256, 0, stream>>>(
      g_s, merge_w, merge_b, g_m, g_st, TT, 64);
  k_bnadd<<<BB*DM*TT/256, 256, 0, stream>>>(g_m, g_st, bn_g, bn_b, g_h);

  // ---- stage 4: up1 (64 -> 1600, shuffle x5) ----
  conv15<64,false,true,true,false,5><<<dim3(1600, TT/1024, BB), 256, 0, stream>>>(
      g_m, up1_w, up1_b, g_u5, nullptr, TT, 320);

  // ---- stage 5: up2 (320 -> 256, shuffle x2) ----
  conv15<320,true,true,true,false,2><<<dim3(256, (TT*5)/1024, BB), 256, 0, stream>>>(
      g_u5, up2_w, up2_b, g_u10, nullptr, TT*5, 128);

  // ---- stage 6: out conv (128 -> 12), fp32 output ----
  conv15<128,true,false,false,false,1><<<dim3(12, (TT*10)/1024, BB), 256, 0, stream>>>(
      g_u10, out_w, out_b, out, nullptr, TT*10, 12);
}

// Round 4
// 1895.779 us; speedup vs baseline: 15.6171x; 15.6171x over previous
//
#include <hip/hip_runtime.h>
#include <hip/hip_bf16.h>
#include <math.h>

typedef __hip_bfloat16 bf16;
typedef __attribute__((ext_vector_type(8))) short short8;   // 8 bf16 in 4 VGPRs
typedef __attribute__((ext_vector_type(4))) float f32x4;

#define BB 16
#define TT 2048
#define DM 64
#define DI 128
#define DSN 16

__device__ __forceinline__ bf16  f2b(float v){ return __float2bfloat16(v); }
__device__ __forceinline__ float b2f(bf16 v){ return __bfloat162float(v); }
__device__ __forceinline__ unsigned short f2bu(float v){
  bf16 b = __float2bfloat16(v); unsigned short u; __builtin_memcpy(&u,&b,2); return u;
}
__device__ __forceinline__ float siluf(float x){ return x / (1.f + __expf(-x)); }
__device__ __forceinline__ float leakyf(float x){ return x >= 0.f ? x : 0.01f*x; }
__device__ __forceinline__ float softplusf(float x){ return x > 20.f ? x : log1pf(__expf(x)); }

__global__ __launch_bounds__(256) void k_zero(float* __restrict__ p, int n){
  int i = blockIdx.x*256 + threadIdx.x;
  if (i < n) p[i] = 0.f;
}

// ---- weight pack: (COUT,CIN,15) fp32 -> B-fragment order bf16 -------------------
// frag id fid = (k*NCH + ch)*NTg + cot ; per frag 64 lanes x 16B:
// lane L holds W[cot*16 + (L&15)][ch*32 + (L>>4)*8 + j][k], j=0..7
__global__ __launch_bounds__(256) void k_pack(
    const float* __restrict__ w, short* __restrict__ wp,
    int COUT, int CIN, int NTg, int NCH)
{
  int i = blockIdx.x*256 + threadIdx.x;
  int lane = i & 63, frag = i >> 6;
  int total = 15*NCH*NTg;
  if (frag >= total) return;
  int cot = frag % NTg; int kc = frag / NTg;
  int ch = kc % NCH;    int k  = kc / NCH;
  int co = cot*16 + (lane & 15);
  int ci0 = ch*32 + (lane >> 4)*8;
  unsigned short v[8];
  #pragma unroll
  for (int j = 0; j < 8; j++)
    v[j] = (co < COUT) ? f2bu(w[((size_t)co*CIN + ci0 + j)*15 + k]) : (unsigned short)0;
  short* dst = wp + (size_t)frag*512 + lane*8;
  *(int4*)dst = *(int4*)v;
}

// ---------------- stage 1: conv_in (12->64, k=15, pad 7) + leaky ------------------
__global__ __launch_bounds__(256) void k_conv_in(
    const float* __restrict__ x, const float* __restrict__ w,
    const float* __restrict__ bias, float* __restrict__ h, bf16* __restrict__ ht)
{
  __shared__ float sx[12][272];
  __shared__ float sw[12][15];
  int tid = threadIdx.x;
  int t0 = blockIdx.x * 256;
  int co = blockIdx.y;
  int b  = blockIdx.z;
  for (int i = tid; i < 12*15; i += 256) sw[i/15][i%15] = w[co*180 + i];
  for (int i = tid; i < 12*270; i += 256) {
    int ci = i/270, L = i%270;
    int tt = t0 - 7 + L;
    sx[ci][L] = (tt >= 0 && tt < TT) ? x[((size_t)b*12+ci)*TT + tt] : 0.f;
  }
  __syncthreads();
  float acc = bias[co];
  #pragma unroll
  for (int ci = 0; ci < 12; ci++) {
    #pragma unroll
    for (int k = 0; k < 15; k++)
      acc += sx[ci][tid+k]*sw[ci][k];
  }
  acc = leakyf(acc);
  int t = t0 + tid;
  h [((size_t)b*DM + co)*TT + t] = acc;
  ht[((size_t)b*TT + t)*DM + co] = f2b(acc);
}

// ---------------- stage 2a: rmsnorm + in_proj (64 -> 256) -------------------------
__global__ __launch_bounds__(256) void k_inproj(
    const bf16* __restrict__ ht, const float* __restrict__ nw,
    const float* __restrict__ w, float* __restrict__ xm, float* __restrict__ z)
{
  __shared__ float sxn[4][64];
  int lane = threadIdx.x & 63, wid = threadIdx.x >> 6;
  int bt = blockIdx.x*4 + wid;
  float v = b2f(ht[(size_t)bt*DM + lane]);
  float ss = v*v;
  #pragma unroll
  for (int o = 32; o; o >>= 1) ss += __shfl_xor(ss, o);
  sxn[wid][lane] = v * rsqrtf(ss*(1.f/64.f) + 1e-5f) * nw[lane];
  __syncthreads();
  #pragma unroll
  for (int i = 0; i < 4; i++) {
    int j = i*64 + lane;
    const float* wr = w + (size_t)j*DM;
    float acc = 0.f;
    #pragma unroll
    for (int d = 0; d < 64; d++) acc += sxn[wid][d]*wr[d];
    if (j < DI) xm[(size_t)bt*DI + j] = acc;
    else        z [(size_t)bt*DI + (j-DI)] = acc;
  }
}

// ---------------- stage 2b: causal depthwise conv k=4 + silu ----------------------
__global__ __launch_bounds__(256) void k_dwconv(
    const float* __restrict__ xm, const float* __restrict__ w,
    const float* __restrict__ bias, float* __restrict__ xc)
{
  int idx = blockIdx.x*256 + threadIdx.x;
  int c = idx & (DI-1);
  int bt = idx / DI;
  int t = bt & (TT-1);
  float acc = bias[c];
  #pragma unroll
  for (int k = 0; k < 4; k++) {
    int tt = t - 3 + k;
    if (tt >= 0) acc += xm[(size_t)(bt - t + tt)*DI + c] * w[c*4+k];
  }
  xc[idx] = siluf(acc);
}

// ---------------- stage 2c: x_proj (128 -> 36) ------------------------------------
__global__ __launch_bounds__(256) void k_xproj(
    const float* __restrict__ xc, const float* __restrict__ w, float* __restrict__ xd)
{
  int idx = blockIdx.x*256 + threadIdx.x;
  int j = idx % 36;
  int bt = idx / 36;
  const float* xr = xc + (size_t)bt*DI;
  const float* wr = w + (size_t)j*DI;
  float acc = 0.f;
  #pragma unroll
  for (int c = 0; c < DI; c++) acc += xr[c]*wr[c];
  xd[idx] = acc;
}

// ---------------- stage 2d: dt_proj + softplus ------------------------------------
__global__ __launch_bounds__(256) void k_delta(
    const float* __restrict__ xd, const float* __restrict__ w,
    const float* __restrict__ bias, float* __restrict__ dlt)
{
  int idx = blockIdx.x*256 + threadIdx.x;
  int c = idx & (DI-1);
  int bt = idx / DI;
  const float* dt = xd + (size_t)bt*36;
  float acc = bias[c];
  #pragma unroll
  for (int r = 0; r < 4; r++) acc += dt[r]*w[c*4+r];
  dlt[idx] = softplusf(acc);
}

// ---------------- stage 2e: selective scan ----------------------------------------
__global__ __launch_bounds__(256) void k_scan(
    const float* __restrict__ dlt, const float* __restrict__ xc,
    const float* __restrict__ xd, const float* __restrict__ A_log,
    const float* __restrict__ Dv, float* __restrict__ y)
{
  int tid = threadIdx.x;
  int n  = tid & 15;
  int dl = tid >> 4;
  int d  = blockIdx.x*16 + dl;
  int b  = blockIdx.y;
  float A  = -__expf(A_log[d*DSN + n]);
  float Dd = Dv[d];
  float hst = 0.f;
  size_t base = (size_t)b*TT;
  float cd = dlt[base*DI + d];
  float cu = xc [base*DI + d];
  float cB = xd [base*36 + 4  + n];
  float cC = xd [base*36 + 20 + n];
  for (int t = 0; t < TT; t++) {
    int tn = (t+1 < TT) ? t+1 : t;
    size_t ib = base + tn;
    float nd = dlt[ib*DI + d];
    float nu = xc [ib*DI + d];
    float nB = xd [ib*36 + 4  + n];
    float nC = xd [ib*36 + 20 + n];
    float dA = __expf(cd*A);
    hst = hst*dA + cd*cu*cB;
    float c = hst*cC;
    c += __shfl_xor(c, 1); c += __shfl_xor(c, 2);
    c += __shfl_xor(c, 4); c += __shfl_xor(c, 8);
    if (n == 0) y[(base+t)*DI + d] = c + cu*Dd;
    cd = nd; cu = nu; cB = nB; cC = nC;
  }
}

// ---------------- stage 2f: gate + out_proj + residual; writes (B,T,64) bf16 ------
__global__ __launch_bounds__(256) void k_outproj(
    const float* __restrict__ y, const float* __restrict__ z,
    const bf16* __restrict__ ht, const float* __restrict__ w,
    bf16* __restrict__ st)
{
  __shared__ float sy[4][128];
  int lane = threadIdx.x & 63, wid = threadIdx.x >> 6;
  int bt = blockIdx.x*4 + wid;
  #pragma unroll
  for (int i = 0; i < 2; i++) {
    int c = i*64 + lane;
    float zz = z[(size_t)bt*DI + c];
    sy[wid][c] = y[(size_t)bt*DI + c] * siluf(zz);
  }
  __syncthreads();
  const float* wr = w + (size_t)lane*DI;
  float acc = b2f(ht[(size_t)bt*DM + lane]);
  #pragma unroll
  for (int c = 0; c < DI; c++) acc += sy[wid][c]*wr[c];
  st[(size_t)bt*DM + lane] = f2b(acc);
}

// ================= MFMA conv15: input (B,Tlen,CIN) bf16 ==========================
// GEMM per tap: C[t][co] += X[t+k-7][ci] * W[co][ci][k].  A=X frag, B=W frag.
// Block: 4 waves x 64 t = 256 t; NC=16*NSUB co per block.
// OUTMODE 0: transposed bf16 out (B, Tlen*R, CTOT=NTg*16/R), pixel-shuffle fused.
// OUTMODE 1: channel-major fp32 out (B, 12, Tlen).
template<int CIN, int NSUB, int R, bool LEAKY, bool STATS, int OUTMODE>
__global__ __launch_bounds__(256) void mfma_conv(
    const bf16* __restrict__ inp, const short* __restrict__ wp,
    const float* __restrict__ bias, void* __restrict__ outv,
    float* __restrict__ stats, int Tlen, int NTg)
{
  constexpr int NCH = CIN/32;
  constexpr int NC  = 16*NSUB;
  constexpr int NCR = NC/R;
  constexpr int STAGE_B = 270*64;
  constexpr int EPI_B = (OUTMODE==0) ? 4*64*NC*2 : 4*16*68*4;
  constexpr int LDSB = (STAGE_B > EPI_B) ? STAGE_B : EPI_B;
  __shared__ __align__(16) char smem[LDSB];

  const int tid  = threadIdx.x;
  const int lane = tid & 63;
  const int wv   = tid >> 6;
  const int lnm  = lane & 15;
  const int quad = lane >> 4;
  const int t0   = blockIdx.x * 256;
  const int by   = blockIdx.y;
  const int b    = blockIdx.z;
  const int wvt  = wv*64;

  f32x4 acc[4][NSUB];
  #pragma unroll
  for (int m = 0; m < 4; m++)
    #pragma unroll
    for (int n = 0; n < NSUB; n++)
      acc[m][n] = (f32x4){0.f,0.f,0.f,0.f};

  for (int ch = 0; ch < NCH; ch++) {
    __syncthreads();
    // stage X tile: rows t0-7 .. t0+262 ; row = 32 ci (64B) in 4 slot-swizzled 16B slots
    {
      int sl = tid & 3;
      for (int r = tid >> 2; r < 270; r += 64) {
        int t = t0 - 7 + r;
        int4 v = {0,0,0,0};
        if (t >= 0 && t < Tlen)
          v = *(const int4*)(inp + ((size_t)((size_t)b*Tlen + t))*CIN + ch*32 + sl*8);
        *(int4*)(&smem[r*64 + ((sl ^ (r & 3)) << 4)]) = v;
      }
    }
    __syncthreads();

    // B frags double-buffered from pre-packed global
    short8 bcur[NSUB], bnxt[NSUB];
    #pragma unroll
    for (int n = 0; n < NSUB; n++) {
      size_t fid = (size_t)((0*NCH + ch)*NTg + by*NSUB + n);
      bcur[n] = *(const short8*)(wp + fid*512 + lane*8);
    }
    for (int k = 0; k < 15; k++) {
      if (k < 14) {
        #pragma unroll
        for (int n = 0; n < NSUB; n++) {
          size_t fid = (size_t)(((k+1)*NCH + ch)*NTg + by*NSUB + n);
          bnxt[n] = *(const short8*)(wp + fid*512 + lane*8);
        }
      }
      short8 af[4];
      #pragma unroll
      for (int m = 0; m < 4; m++) {
        int row = wvt + m*16 + lnm + k;
        af[m] = *(const short8*)(&smem[row*64 + ((quad ^ (row & 3)) << 4)]);
      }
      #pragma unroll
      for (int m = 0; m < 4; m++)
        #pragma unroll
        for (int n = 0; n < NSUB; n++)
          acc[m][n] = __builtin_amdgcn_mfma_f32_16x16x32_bf16(af[m], bcur[n], acc[m][n], 0, 0, 0);
      #pragma unroll
      for (int n = 0; n < NSUB; n++) bcur[n] = bnxt[n];
    }
  }

  // bias
  #pragma unroll
  for (int n = 0; n < NSUB; n++) {
    float bv = bias[by*NC + n*16 + lnm];
    #pragma unroll
    for (int m = 0; m < 4; m++) {
      acc[m][n].x += bv; acc[m][n].y += bv; acc[m][n].z += bv; acc[m][n].w += bv;
    }
  }
  if (STATS) {
    #pragma unroll
    for (int n = 0; n < NSUB; n++) {
      float s1 = 0.f, s2 = 0.f;
      #pragma unroll
      for (int m = 0; m < 4; m++) {
        f32x4 a = acc[m][n];
        s1 += a.x + a.y + a.z + a.w;
        s2 += a.x*a.x + a.y*a.y + a.z*a.z + a.w*a.w;
      }
      s1 += __shfl_xor(s1, 16); s1 += __shfl_xor(s1, 32);
      s2 += __shfl_xor(s2, 16); s2 += __shfl_xor(s2, 32);
      if (quad == 0) {
        atomicAdd(&stats[by*NC + n*16 + lnm], s1);
        atomicAdd(&stats[64 + by*NC + n*16 + lnm], s2);
      }
    }
  }
  if (LEAKY) {
    #pragma unroll
    for (int m = 0; m < 4; m++)
      #pragma unroll
      for (int n = 0; n < NSUB; n++) {
        acc[m][n].x = leakyf(acc[m][n].x); acc[m][n].y = leakyf(acc[m][n].y);
        acc[m][n].z = leakyf(acc[m][n].z); acc[m][n].w = leakyf(acc[m][n].w);
      }
  }

  __syncthreads();   // done with X tile; smem reused for epilogue

  if (OUTMODE == 0) {
    // stage C in (t, p*NCR+c) order, then coalesced transposed global write
    short* Cw = (short*)smem + wv*64*NC;
    #pragma unroll
    for (int m = 0; m < 4; m++)
      #pragma unroll
      for (int n = 0; n < NSUB; n++) {
        int co = n*16 + lnm;
        int p = co % R, c = co / R;
        float vv[4] = {acc[m][n].x, acc[m][n].y, acc[m][n].z, acc[m][n].w};
        #pragma unroll
        for (int r = 0; r < 4; r++) {
          int t = m*16 + quad*4 + r;
          Cw[t*NC + p*NCR + c] = (short)f2bu(vv[r]);
        }
      }
    const int SPT = NC/8;
    const int CTOT = NTg*16/R;
    bf16* outp = (bf16*)outv;
    size_t brow = (size_t)b * ((size_t)Tlen*R);
    for (int j = lane; j < 64*SPT; j += 64) {
      int t = j / SPT, sl = j % SPT;
      int cosw = sl*8;
      int p = cosw / NCR, csl = cosw % NCR;
      int tout = (t0 + wvt + t)*R + p;
      size_t ga = (brow + tout)*(size_t)CTOT + (size_t)by*NCR + csl;
      *(int4*)((short*)outp + ga) = *(const int4*)(Cw + t*NC + cosw);
    }
  } else {
    // channel-major fp32, COUT=12 valid of 16
    float* Cw = (float*)smem + wv*(16*68);
    #pragma unroll
    for (int m = 0; m < 4; m++) {
      float vv[4] = {acc[m][0].x, acc[m][0].y, acc[m][0].z, acc[m][0].w};
      #pragma unroll
      for (int r = 0; r < 4; r++) {
        int t = m*16 + quad*4 + r;
        Cw[lnm*68 + t] = vv[r];
      }
    }
    float* outf = (float*)outv;
    for (int j = lane; j < 12*16; j += 64) {
      int co = j >> 4, t4 = (j & 15)*4;
      size_t ga = ((size_t)b*12 + co)*(size_t)Tlen + t0 + wvt + t4;
      *(float4*)(outf + ga) = *(const float4*)(Cw + co*68 + t4);
    }
  }
}

// ---------------- BN apply + residual; (B,T,64) bf16 out for up1 -----------------
__global__ __launch_bounds__(256) void k_bnadd2(
    const bf16* __restrict__ m2, const float* __restrict__ stats,
    const float* __restrict__ g, const float* __restrict__ bb,
    const float* __restrict__ h, bf16* __restrict__ mt)
{
  int idx = blockIdx.x*256 + threadIdx.x;   // (b*T + t)*64 + c
  int c = idx & 63;
  int t = (idx >> 6) & (TT-1);
  int b = idx >> 17;
  const float cnt = (float)(BB*TT);
  float mu  = stats[c] / cnt;
  float var = stats[64+c] / cnt - mu*mu;
  float inv = rsqrtf(var + 1e-5f);
  float v = b2f(m2[idx]);
  float hv = h[((size_t)b*64 + c)*TT + t];
  mt[idx] = f2b((v - mu)*inv*g[c] + bb[c] + hv);
}

// ==================================================================================
extern "C" void kernel_launch(void* const* d_in, const int* in_sizes, int n_in,
                              void* d_out, int out_size, void* d_ws, size_t ws_size,
                              hipStream_t stream)
{
  const float* in_x       = (const float*)d_in[0];
  const float* conv_in_w  = (const float*)d_in[1];
  const float* conv_in_b  = (const float*)d_in[2];
  const float* norm_w     = (const float*)d_in[3];
  const float* in_proj_w  = (const float*)d_in[4];
  const float* dwconv_w   = (const float*)d_in[5];
  const float* dwconv_b   = (const float*)d_in[6];
  const float* x_proj_w   = (const float*)d_in[7];
  const float* dt_proj_w  = (const float*)d_in[8];
  const float* dt_proj_b  = (const float*)d_in[9];
  const float* A_log      = (const float*)d_in[10];
  const float* Dvec       = (const float*)d_in[11];
  const float* out_proj_w = (const float*)d_in[12];
  const float* merge_w    = (const float*)d_in[13];
  const float* merge_b    = (const float*)d_in[14];
  const float* bn_g       = (const float*)d_in[15];
  const float* bn_b       = (const float*)d_in[16];
  const float* up1_w      = (const float*)d_in[17];
  const float* up1_b      = (const float*)d_in[18];
  const float* up2_w      = (const float*)d_in[19];
  const float* up2_b      = (const float*)d_in[20];
  const float* out_w      = (const float*)d_in[21];
  const float* out_b      = (const float*)d_in[22];
  float* out = (float*)d_out;

  size_t off = 0;
  auto take = [&](size_t bytes) -> void* {
    void* p = (char*)d_ws + off;
    off += (bytes + 255) & ~(size_t)255;
    return p;
  };
  const size_t F_BDMT = (size_t)BB*DM*TT;    // 2,097,152
  const size_t F_BTDI = (size_t)BB*TT*DI;    // 4,194,304
  const size_t F_XDBL = (size_t)BB*TT*36;
  float* g_h   = (float*)take(F_BDMT*4);         // (B,64,T) fp32, residual hold
  bf16*  g_ht  = (bf16*) take(F_BDMT*2);         // (B,T,64) bf16
  bf16*  g_st  = (bf16*) take(F_BDMT*2);         // mamba out (B,T,64) bf16
  bf16*  g_m2  = (bf16*) take(F_BDMT*2);         // merge conv out (B,T,64) bf16
  bf16*  g_mt  = (bf16*) take(F_BDMT*2);         // BN+res out (B,T,64) bf16
  float* g_stt = (float*)take(512);              // BN stats
  short* wp_mg = (short*)take((size_t)15*2*4 *512*2);   // merge: NCH=2, NTg=4
  short* wp_u1 = (short*)take((size_t)15*2*100*512*2);  // up1
  short* wp_u2 = (short*)take((size_t)15*10*16*512*2);  // up2
  short* wp_oc = (short*)take((size_t)15*4*1  *512*2);  // out
  size_t mamba_base = off;
  float* g_xm  = (float*)take(F_BTDI*4);
  float* g_z   = (float*)take(F_BTDI*4);
  float* g_xc  = (float*)take(F_BTDI*4);
  float* g_xd  = (float*)take(F_XDBL*4);
  float* g_dl  = (float*)take(F_BTDI*4);
  float* g_y   = (float*)take(F_BTDI*4);
  bf16*  g_u10 = (bf16*)((char*)d_ws + mamba_base);   // (B,20480,128) bf16, 84MB overlay
  bf16*  g_u5  = (bf16*)take((size_t)BB*10240*320*2); // (B,10240,320) bf16, 105MB
  if (off > ws_size) return;

  // ---- packs + stats zero (independent of pipeline) ----
  k_zero<<<1, 256, 0, stream>>>(g_stt, 128);
  k_pack<<<(15*2*4*64+255)/256, 256, 0, stream>>>(merge_w, wp_mg, 64, 64, 4, 2);
  k_pack<<<(15*2*100*64+255)/256, 256, 0, stream>>>(up1_w, wp_u1, 1600, 64, 100, 2);
  k_pack<<<(15*10*16*64+255)/256, 256, 0, stream>>>(up2_w, wp_u2, 256, 320, 16, 10);
  k_pack<<<(15*4*1*64+255)/256, 256, 0, stream>>>(out_w, wp_oc, 12, 128, 1, 4);

  // ---- stage 1 ----
  k_conv_in<<<dim3(TT/256, DM, BB), 256, 0, stream>>>(in_x, conv_in_w, conv_in_b, g_h, g_ht);

  // ---- stage 2: mamba ----
  k_inproj <<<BB*TT/4, 256, 0, stream>>>(g_ht, norm_w, in_proj_w, g_xm, g_z);
  k_dwconv <<<BB*TT*DI/256, 256, 0, stream>>>(g_xm, dwconv_w, dwconv_b, g_xc);
  k_xproj  <<<BB*TT*36/256, 256, 0, stream>>>(g_xc, x_proj_w, g_xd);
  k_delta  <<<BB*TT*DI/256, 256, 0, stream>>>(g_xd, dt_proj_w, dt_proj_b, g_dl);
  k_scan   <<<dim3(DI/16, BB), 256, 0, stream>>>(g_dl, g_xc, g_xd, A_log, Dvec, g_y);
  k_outproj<<<BB*TT/4, 256, 0, stream>>>(g_y, g_z, g_ht, out_proj_w, g_st);

  // ---- stage 3: merge conv (MFMA) + BN + residual ----
  mfma_conv<64,4,1,false,true,0><<<dim3(TT/256, 1, BB), 256, 0, stream>>>(
      g_st, wp_mg, merge_b, g_m2, g_stt, TT, 4);
  k_bnadd2<<<BB*TT*64/256, 256, 0, stream>>>(g_m2, g_stt, bn_g, bn_b, g_h, g_mt);

  // ---- stage 4: up1 (64 -> 1600, shuffle x5) ----
  mfma_conv<64,5,5,true,false,0><<<dim3(TT/256, 20, BB), 256, 0, stream>>>(
      g_mt, wp_u1, up1_b, g_u5, nullptr, TT, 100);

  // ---- stage 5: up2 (320 -> 256, shuffle x2) ----
  mfma_conv<320,4,2,true,false,0><<<dim3(TT*5/256, 4, BB), 256, 0, stream>>>(
      g_u5, wp_u2, up2_b, g_u10, nullptr, TT*5, 16);

  // ---- stage 6: out conv (128 -> 12), fp32 channel-major ----
  mfma_conv<128,1,1,false,false,1><<<dim3(TT*10/256, 1, BB), 256, 0, stream>>>(
      g_u10, wp_oc, out_b, out, nullptr, TT*10, 1);
}

// Round 5
// 889.159 us; speedup vs baseline: 33.2972x; 2.1321x over previous
//
#include <hip/hip_runtime.h>
#include <hip/hip_bf16.h>
#include <math.h>

typedef __hip_bfloat16 bf16;
typedef __attribute__((ext_vector_type(8))) short short8;   // 8 bf16 in 4 VGPRs
typedef __attribute__((ext_vector_type(4))) float f32x4;

#define BB 16
#define TT 2048
#define DM 64
#define DI 128
#define DSN 16
#define NCHK 32
#define CLEN 64

union U8 { int4 i4; unsigned short u[8]; };

__device__ __forceinline__ bf16  f2b(float v){ return __float2bfloat16(v); }
__device__ __forceinline__ float b2f(bf16 v){ return __bfloat162float(v); }
__device__ __forceinline__ unsigned short f2bu(float v){
  bf16 b = __float2bfloat16(v); unsigned short u; __builtin_memcpy(&u,&b,2); return u;
}
__device__ __forceinline__ float bu2f(unsigned short u){
  unsigned int x = ((unsigned int)u) << 16; float f; __builtin_memcpy(&f,&x,4); return f;
}
__device__ __forceinline__ float siluf(float x){ return x / (1.f + __expf(-x)); }
__device__ __forceinline__ float leakyf(float x){ return x >= 0.f ? x : 0.01f*x; }
__device__ __forceinline__ float softplusf(float x){ return x > 20.f ? x : log1pf(__expf(x)); }

__global__ __launch_bounds__(256) void k_zero(float* __restrict__ p, int n){
  int i = blockIdx.x*256 + threadIdx.x;
  if (i < n) p[i] = 0.f;
}

// ---- weight pack: (COUT,CIN,NTAP) fp32 -> B-fragment order bf16 ------------------
// fid = (k*NCH + ch)*NTg + cot ; lane L holds W[cot*16+(L&15)][ch*32+(L>>4)*8+j][k]
__global__ __launch_bounds__(256) void k_pack(
    const float* __restrict__ w, short* __restrict__ wp,
    int COUT, int CIN, int NTg, int NCH, int NTAP)
{
  int i = blockIdx.x*256 + threadIdx.x;
  int lane = i & 63, frag = i >> 6;
  int total = NTAP*NCH*NTg;
  if (frag >= total) return;
  int cot = frag % NTg; int kc = frag / NTg;
  int ch = kc % NCH;    int k  = kc / NCH;
  int co = cot*16 + (lane & 15);
  int ci0 = ch*32 + (lane >> 4)*8;
  unsigned short v[8];
  #pragma unroll
  for (int j = 0; j < 8; j++)
    v[j] = (co < COUT) ? f2bu(w[((size_t)co*CIN + ci0 + j)*NTAP + k]) : (unsigned short)0;
  short* dst = wp + (size_t)frag*512 + lane*8;
  *(int4*)dst = *(int4*)v;
}

// ---------------- stage 1: conv_in (12->64, k=15, pad 7) + leaky ------------------
__global__ __launch_bounds__(256) void k_conv_in(
    const float* __restrict__ x, const float* __restrict__ w,
    const float* __restrict__ bias, float* __restrict__ h, bf16* __restrict__ ht)
{
  __shared__ float sx[12][272];
  __shared__ float sw[12][15];
  int tid = threadIdx.x;
  int t0 = blockIdx.x * 256;
  int co = blockIdx.y;
  int b  = blockIdx.z;
  for (int i = tid; i < 12*15; i += 256) sw[i/15][i%15] = w[co*180 + i];
  for (int i = tid; i < 12*270; i += 256) {
    int ci = i/270, L = i%270;
    int tt = t0 - 7 + L;
    sx[ci][L] = (tt >= 0 && tt < TT) ? x[((size_t)b*12+ci)*TT + tt] : 0.f;
  }
  __syncthreads();
  float acc = bias[co];
  #pragma unroll
  for (int ci = 0; ci < 12; ci++) {
    #pragma unroll
    for (int k = 0; k < 15; k++)
      acc += sx[ci][tid+k]*sw[ci][k];
  }
  acc = leakyf(acc);
  int t = t0 + tid;
  h [((size_t)b*DM + co)*TT + t] = acc;
  ht[((size_t)b*TT + t)*DM + co] = f2b(acc);
}

// ---------- stage 2a: fused rmsnorm + in_proj MFMA (64 -> 256) --------------------
// tile 64 t per block; wave wv covers co [wv*64, wv*64+64)
__global__ __launch_bounds__(256) void k_inproj_mfma(
    const bf16* __restrict__ ht, const float* __restrict__ nw,
    const short* __restrict__ wp, bf16* __restrict__ xm, bf16* __restrict__ z)
{
  __shared__ short sxa[64*128];
  __shared__ float sred[64][4];
  const int tid = threadIdx.x;
  const int lane = tid & 63, wv = tid >> 6;
  const int lnm = lane & 15, quad = lane >> 4;
  const size_t bt0 = (size_t)blockIdx.x * 64;

  // staging + rmsnorm: thread = (row, 16-ch part)
  {
    int row = tid >> 2, part = tid & 3, ch0 = part*16;
    const short* src = (const short*)ht + (bt0 + row)*64 + ch0;
    U8 p0, p1; p0.i4 = *(const int4*)src; p1.i4 = *(const int4*)(src + 8);
    float f[16]; float ss = 0.f;
    #pragma unroll
    for (int j = 0; j < 8; j++) { f[j] = bu2f(p0.u[j]); f[8+j] = bu2f(p1.u[j]); }
    #pragma unroll
    for (int j = 0; j < 16; j++) ss += f[j]*f[j];
    sred[row][part] = ss;
    __syncthreads();
    float tot = sred[row][0]+sred[row][1]+sred[row][2]+sred[row][3];
    float sc = rsqrtf(tot*(1.f/64.f) + 1e-5f);
    U8 o0, o1;
    #pragma unroll
    for (int j = 0; j < 8; j++) {
      o0.u[j] = f2bu(f[j]  *sc*nw[ch0+j]);
      o1.u[j] = f2bu(f[8+j]*sc*nw[ch0+8+j]);
    }
    int s0 = part*2, s1 = part*2+1;
    *(int4*)(sxa + row*128 + ((s0 ^ (row&7))<<3)) = o0.i4;
    *(int4*)(sxa + row*128 + ((s1 ^ (row&7))<<3)) = o1.i4;
  }
  __syncthreads();

  f32x4 acc[4][4];
  #pragma unroll
  for (int m = 0; m < 4; m++)
    #pragma unroll
    for (int n = 0; n < 4; n++) acc[m][n] = (f32x4){0.f,0.f,0.f,0.f};

  #pragma unroll
  for (int kc = 0; kc < 2; kc++) {
    short8 bfr[4];
    #pragma unroll
    for (int n = 0; n < 4; n++) {
      int fid = kc*16 + wv*4 + n;
      bfr[n] = *(const short8*)(wp + (size_t)fid*512 + lane*8);
    }
    #pragma unroll
    for (int m = 0; m < 4; m++) {
      int r2 = m*16 + lnm;
      short8 a = *(const short8*)(sxa + r2*128 + (((kc*4+quad) ^ (r2&7))<<3));
      #pragma unroll
      for (int n = 0; n < 4; n++)
        acc[m][n] = __builtin_amdgcn_mfma_f32_16x16x32_bf16(a, bfr[n], acc[m][n], 0, 0, 0);
    }
  }

  #pragma unroll
  for (int m = 0; m < 4; m++)
    #pragma unroll
    for (int n = 0; n < 4; n++) {
      int co = wv*64 + n*16 + lnm;
      float v[4] = {acc[m][n].x, acc[m][n].y, acc[m][n].z, acc[m][n].w};
      #pragma unroll
      for (int r = 0; r < 4; r++) {
        size_t t = bt0 + m*16 + quad*4 + r;
        if (co < 128) xm[t*128 + co]       = f2b(v[r]);
        else          z [t*128 + (co-128)] = f2b(v[r]);
      }
    }
}

// ---------------- stage 2b: causal depthwise conv k=4 + silu ----------------------
__global__ __launch_bounds__(256) void k_dwconv(
    const bf16* __restrict__ xm, const float* __restrict__ w,
    const float* __restrict__ bias, float* __restrict__ xcf, bf16* __restrict__ xcb)
{
  int idx = blockIdx.x*256 + threadIdx.x;        // bt*128 + c
  int c = idx & (DI-1);
  int bt = idx >> 7;
  int t = bt & (TT-1);
  float acc = bias[c];
  #pragma unroll
  for (int k = 0; k < 4; k++) {
    int tt = t - 3 + k;
    if (tt >= 0) acc += b2f(xm[(size_t)(bt - 3 + k)*DI + c]) * w[c*4+k];
  }
  float v = siluf(acc);
  xcf[idx] = v;
  xcb[idx] = f2b(v);
}

// ---------- stage 2c: x_proj MFMA (128 -> 48, 36 valid), fp32 out -----------------
__global__ __launch_bounds__(256) void k_xproj_mfma(
    const bf16* __restrict__ xcb, const short* __restrict__ wp, float* __restrict__ xd)
{
  __shared__ __align__(16) char smem[256*64];
  const int tid = threadIdx.x;
  const int lane = tid & 63, wv = tid >> 6;
  const int lnm = lane & 15, quad = lane >> 4;
  const size_t bt0 = (size_t)blockIdx.x * 256;
  const int wvt = wv*64;

  f32x4 acc[4][3];
  #pragma unroll
  for (int m = 0; m < 4; m++)
    #pragma unroll
    for (int n = 0; n < 3; n++) acc[m][n] = (f32x4){0.f,0.f,0.f,0.f};

  for (int ch = 0; ch < 4; ch++) {
    __syncthreads();
    int sl = tid & 3;
    for (int r = tid >> 2; r < 256; r += 64) {
      int4 v = *(const int4*)((const short*)xcb + (bt0 + r)*128 + ch*32 + sl*8);
      *(int4*)(&smem[r*64 + ((sl ^ (r & 3)) << 4)]) = v;
    }
    __syncthreads();
    short8 bfr[3];
    #pragma unroll
    for (int n = 0; n < 3; n++)
      bfr[n] = *(const short8*)(wp + (size_t)(ch*3+n)*512 + lane*8);
    #pragma unroll
    for (int m = 0; m < 4; m++) {
      int row = wvt + m*16 + lnm;
      short8 a = *(const short8*)(&smem[row*64 + ((quad ^ (row & 3)) << 4)]);
      #pragma unroll
      for (int n = 0; n < 3; n++)
        acc[m][n] = __builtin_amdgcn_mfma_f32_16x16x32_bf16(a, bfr[n], acc[m][n], 0, 0, 0);
    }
  }
  #pragma unroll
  for (int m = 0; m < 4; m++)
    #pragma unroll
    for (int n = 0; n < 3; n++) {
      int cho = n*16 + lnm;
      float v[4] = {acc[m][n].x, acc[m][n].y, acc[m][n].z, acc[m][n].w};
      #pragma unroll
      for (int r = 0; r < 4; r++) {
        size_t t = bt0 + wvt + m*16 + quad*4 + r;
        xd[t*48 + cho] = v[r];
      }
    }
}

// ---------------- stage 2d: dt_proj + softplus ------------------------------------
__global__ __launch_bounds__(256) void k_delta(
    const float* __restrict__ xd, const float* __restrict__ w,
    const float* __restrict__ bias, float* __restrict__ dlt)
{
  int idx = blockIdx.x*256 + threadIdx.x;        // bt*128 + c
  int c = idx & (DI-1);
  int bt = idx >> 7;
  const float* dt = xd + (size_t)bt*48;
  float acc = bias[c];
  #pragma unroll
  for (int r = 0; r < 4; r++) acc += dt[r]*w[c*4+r];
  dlt[idx] = softplusf(acc);
}

// ---------------- stage 2e: chunked selective scan --------------------------------
__global__ __launch_bounds__(256) void k_scan_sum(
    const float* __restrict__ dlt, const float* __restrict__ xcf,
    const float* __restrict__ xd, const float* __restrict__ A_log,
    float* __restrict__ gP, float* __restrict__ gS)
{
  int tid = threadIdx.x;
  int n = tid & 15, dl = tid >> 4;
  int d = blockIdx.x*16 + dl;
  int b = blockIdx.y, ck = blockIdx.z;
  float A = -__expf(A_log[d*DSN + n]);
  float P = 1.f, h = 0.f;
  size_t base = (size_t)b*TT + (size_t)ck*CLEN;
  for (int i = 0; i < CLEN; i++) {
    size_t ib = base + i;
    float dd = dlt[ib*DI + d];
    float uu = xcf[ib*DI + d];
    float Bv = xd [ib*48 + 4 + n];
    float dA = __expf(dd*A);
    h = h*dA + dd*uu*Bv;
    P *= dA;
  }
  size_t idx = (((size_t)b*NCHK + ck)*DI + d)*DSN + n;
  gP[idx] = P; gS[idx] = h;
}

__global__ __launch_bounds__(256) void k_scan_comb(
    const float* __restrict__ gP, const float* __restrict__ gS,
    float* __restrict__ ghs)
{
  int idx = blockIdx.x*256 + threadIdx.x;   // (b*128+d)*16+n
  int n = idx & 15, d = (idx >> 4) & 127, b = idx >> 11;
  float h = 0.f;
  for (int c = 0; c < NCHK; c++) {
    size_t j = (((size_t)b*NCHK + c)*DI + d)*DSN + n;
    ghs[j] = h;
    h = gP[j]*h + gS[j];
  }
}

__global__ __launch_bounds__(256) void k_scan_out(
    const float* __restrict__ dlt, const float* __restrict__ xcf,
    const float* __restrict__ xd, const float* __restrict__ A_log,
    const float* __restrict__ Dv, const float* __restrict__ ghs,
    float* __restrict__ y)
{
  int tid = threadIdx.x;
  int n = tid & 15, dl = tid >> 4;
  int d = blockIdx.x*16 + dl;
  int b = blockIdx.y, ck = blockIdx.z;
  float A = -__expf(A_log[d*DSN + n]);
  float Dd = Dv[d];
  size_t idx = (((size_t)b*NCHK + ck)*DI + d)*DSN + n;
  float h = ghs[idx];
  size_t base = (size_t)b*TT + (size_t)ck*CLEN;
  for (int i = 0; i < CLEN; i++) {
    size_t ib = base + i;
    float dd = dlt[ib*DI + d];
    float uu = xcf[ib*DI + d];
    float Bv = xd [ib*48 + 4  + n];
    float Cv = xd [ib*48 + 20 + n];
    float dA = __expf(dd*A);
    h = h*dA + dd*uu*Bv;
    float c = h*Cv;
    c += __shfl_xor(c, 1); c += __shfl_xor(c, 2);
    c += __shfl_xor(c, 4); c += __shfl_xor(c, 8);
    if (n == 0) y[ib*DI + d] = c + uu*Dd;
  }
}

// ---------- stage 2f: gate + out_proj MFMA (128 -> 64) + residual -----------------
__global__ __launch_bounds__(256) void k_outproj_mfma(
    const float* __restrict__ gy, const bf16* __restrict__ gz,
    const bf16* __restrict__ ht, const short* __restrict__ wp,
    bf16* __restrict__ st)
{
  __shared__ __align__(16) char smem[256*64];
  const int tid = threadIdx.x;
  const int lane = tid & 63, wv = tid >> 6;
  const int lnm = lane & 15, quad = lane >> 4;
  const size_t bt0 = (size_t)blockIdx.x * 256;
  const int wvt = wv*64;

  f32x4 acc[4][4];
  #pragma unroll
  for (int m = 0; m < 4; m++)
    #pragma unroll
    for (int n = 0; n < 4; n++) acc[m][n] = (f32x4){0.f,0.f,0.f,0.f};

  for (int ch = 0; ch < 4; ch++) {
    __syncthreads();
    int sl = tid & 3;
    for (int r = tid >> 2; r < 256; r += 64) {
      size_t base = (bt0 + r)*(size_t)DI + ch*32 + sl*8;
      float4 y0 = *(const float4*)(gy + base);
      float4 y1 = *(const float4*)(gy + base + 4);
      U8 zz; zz.i4 = *(const int4*)((const short*)gz + base);
      float yv[8] = {y0.x, y0.y, y0.z, y0.w, y1.x, y1.y, y1.z, y1.w};
      U8 o;
      #pragma unroll
      for (int j = 0; j < 8; j++)
        o.u[j] = f2bu(yv[j] * siluf(bu2f(zz.u[j])));
      *(int4*)(&smem[r*64 + ((sl ^ (r & 3)) << 4)]) = o.i4;
    }
    __syncthreads();
    short8 bfr[4];
    #pragma unroll
    for (int n = 0; n < 4; n++)
      bfr[n] = *(const short8*)(wp + (size_t)(ch*4+n)*512 + lane*8);
    #pragma unroll
    for (int m = 0; m < 4; m++) {
      int row = wvt + m*16 + lnm;
      short8 a = *(const short8*)(&smem[row*64 + ((quad ^ (row & 3)) << 4)]);
      #pragma unroll
      for (int n = 0; n < 4; n++)
        acc[m][n] = __builtin_amdgcn_mfma_f32_16x16x32_bf16(a, bfr[n], acc[m][n], 0, 0, 0);
    }
  }
  #pragma unroll
  for (int m = 0; m < 4; m++)
    #pragma unroll
    for (int n = 0; n < 4; n++) {
      int cho = n*16 + lnm;
      float v[4] = {acc[m][n].x, acc[m][n].y, acc[m][n].z, acc[m][n].w};
      #pragma unroll
      for (int r = 0; r < 4; r++) {
        size_t t = bt0 + wvt + m*16 + quad*4 + r;
        st[t*DM + cho] = f2b(v[r] + b2f(ht[t*DM + cho]));
      }
    }
}

// ================= MFMA conv15: input (B,Tlen,CIN) bf16 ==========================
template<int CIN, int NSUB, int R, bool LEAKY, bool STATS, int OUTMODE>
__global__ __launch_bounds__(256) void mfma_conv(
    const bf16* __restrict__ inp, const short* __restrict__ wp,
    const float* __restrict__ bias, void* __restrict__ outv,
    float* __restrict__ stats, int Tlen, int NTg)
{
  constexpr int NCH = CIN/32;
  constexpr int NC  = 16*NSUB;
  constexpr int NCR = NC/R;
  constexpr int STAGE_B = 270*64;
  constexpr int EPI_B = (OUTMODE==0) ? 4*64*NC*2 : 4*16*68*4;
  constexpr int LDSB = (STAGE_B > EPI_B) ? STAGE_B : EPI_B;
  __shared__ __align__(16) char smem[LDSB];

  const int tid  = threadIdx.x;
  const int lane = tid & 63;
  const int wv   = tid >> 6;
  const int lnm  = lane & 15;
  const int quad = lane >> 4;
  const int t0   = blockIdx.x * 256;
  const int by   = blockIdx.y;
  const int b    = blockIdx.z;
  const int wvt  = wv*64;

  f32x4 acc[4][NSUB];
  #pragma unroll
  for (int m = 0; m < 4; m++)
    #pragma unroll
    for (int n = 0; n < NSUB; n++)
      acc[m][n] = (f32x4){0.f,0.f,0.f,0.f};

  for (int ch = 0; ch < NCH; ch++) {
    __syncthreads();
    {
      int sl = tid & 3;
      for (int r = tid >> 2; r < 270; r += 64) {
        int t = t0 - 7 + r;
        int4 v = {0,0,0,0};
        if (t >= 0 && t < Tlen)
          v = *(const int4*)(inp + ((size_t)((size_t)b*Tlen + t))*CIN + ch*32 + sl*8);
        *(int4*)(&smem[r*64 + ((sl ^ (r & 3)) << 4)]) = v;
      }
    }
    __syncthreads();

    short8 bcur[NSUB], bnxt[NSUB];
    #pragma unroll
    for (int n = 0; n < NSUB; n++) {
      size_t fid = (size_t)((0*NCH + ch)*NTg + by*NSUB + n);
      bcur[n] = *(const short8*)(wp + fid*512 + lane*8);
    }
    for (int k = 0; k < 15; k++) {
      if (k < 14) {
        #pragma unroll
        for (int n = 0; n < NSUB; n++) {
          size_t fid = (size_t)(((k+1)*NCH + ch)*NTg + by*NSUB + n);
          bnxt[n] = *(const short8*)(wp + fid*512 + lane*8);
        }
      }
      short8 af[4];
      #pragma unroll
      for (int m = 0; m < 4; m++) {
        int row = wvt + m*16 + lnm + k;
        af[m] = *(const short8*)(&smem[row*64 + ((quad ^ (row & 3)) << 4)]);
      }
      #pragma unroll
      for (int m = 0; m < 4; m++)
        #pragma unroll
        for (int n = 0; n < NSUB; n++)
          acc[m][n] = __builtin_amdgcn_mfma_f32_16x16x32_bf16(af[m], bcur[n], acc[m][n], 0, 0, 0);
      #pragma unroll
      for (int n = 0; n < NSUB; n++) bcur[n] = bnxt[n];
    }
  }

  #pragma unroll
  for (int n = 0; n < NSUB; n++) {
    float bv = bias[by*NC + n*16 + lnm];
    #pragma unroll
    for (int m = 0; m < 4; m++) {
      acc[m][n].x += bv; acc[m][n].y += bv; acc[m][n].z += bv; acc[m][n].w += bv;
    }
  }
  if (STATS) {
    #pragma unroll
    for (int n = 0; n < NSUB; n++) {
      float s1 = 0.f, s2 = 0.f;
      #pragma unroll
      for (int m = 0; m < 4; m++) {
        f32x4 a = acc[m][n];
        s1 += a.x + a.y + a.z + a.w;
        s2 += a.x*a.x + a.y*a.y + a.z*a.z + a.w*a.w;
      }
      s1 += __shfl_xor(s1, 16); s1 += __shfl_xor(s1, 32);
      s2 += __shfl_xor(s2, 16); s2 += __shfl_xor(s2, 32);
      if (quad == 0) {
        atomicAdd(&stats[by*NC + n*16 + lnm], s1);
        atomicAdd(&stats[64 + by*NC + n*16 + lnm], s2);
      }
    }
  }
  if (LEAKY) {
    #pragma unroll
    for (int m = 0; m < 4; m++)
      #pragma unroll
      for (int n = 0; n < NSUB; n++) {
        acc[m][n].x = leakyf(acc[m][n].x); acc[m][n].y = leakyf(acc[m][n].y);
        acc[m][n].z = leakyf(acc[m][n].z); acc[m][n].w = leakyf(acc[m][n].w);
      }
  }

  __syncthreads();

  if (OUTMODE == 0) {
    short* Cw = (short*)smem + wv*64*NC;
    #pragma unroll
    for (int m = 0; m < 4; m++)
      #pragma unroll
      for (int n = 0; n < NSUB; n++) {
        int co = n*16 + lnm;
        int p = co % R, c = co / R;
        float vv[4] = {acc[m][n].x, acc[m][n].y, acc[m][n].z, acc[m][n].w};
        #pragma unroll
        for (int r = 0; r < 4; r++) {
          int t = m*16 + quad*4 + r;
          Cw[t*NC + p*NCR + c] = (short)f2bu(vv[r]);
        }
      }
    const int SPT = NC/8;
    const int CTOT = NTg*16/R;
    bf16* outp = (bf16*)outv;
    size_t brow = (size_t)b * ((size_t)Tlen*R);
    for (int j = lane; j < 64*SPT; j += 64) {
      int t = j / SPT, sl = j % SPT;
      int cosw = sl*8;
      int p = cosw / NCR, csl = cosw % NCR;
      int tout = (t0 + wvt + t)*R + p;
      size_t ga = (brow + tout)*(size_t)CTOT + (size_t)by*NCR + csl;
      *(int4*)((short*)outp + ga) = *(const int4*)(Cw + t*NC + cosw);
    }
  } else {
    float* Cw = (float*)smem + wv*(16*68);
    #pragma unroll
    for (int m = 0; m < 4; m++) {
      float vv[4] = {acc[m][0].x, acc[m][0].y, acc[m][0].z, acc[m][0].w};
      #pragma unroll
      for (int r = 0; r < 4; r++) {
        int t = m*16 + quad*4 + r;
        Cw[lnm*68 + t] = vv[r];
      }
    }
    float* outf = (float*)outv;
    for (int j = lane; j < 12*16; j += 64) {
      int co = j >> 4, t4 = (j & 15)*4;
      size_t ga = ((size_t)b*12 + co)*(size_t)Tlen + t0 + wvt + t4;
      *(float4*)(outf + ga) = *(const float4*)(Cw + co*68 + t4);
    }
  }
}

// ---------------- BN apply + residual; (B,T,64) bf16 out for up1 -----------------
__global__ __launch_bounds__(256) void k_bnadd2(
    const bf16* __restrict__ m2, const float* __restrict__ stats,
    const float* __restrict__ g, const float* __restrict__ bb,
    const float* __restrict__ h, bf16* __restrict__ mt)
{
  int idx = blockIdx.x*256 + threadIdx.x;   // (b*T + t)*64 + c
  int c = idx & 63;
  int t = (idx >> 6) & (TT-1);
  int b = idx >> 17;
  const float cnt = (float)(BB*TT);
  float mu  = stats[c] / cnt;
  float var = stats[64+c] / cnt - mu*mu;
  float inv = rsqrtf(var + 1e-5f);
  float v = b2f(m2[idx]);
  float hv = h[((size_t)b*64 + c)*TT + t];
  mt[idx] = f2b((v - mu)*inv*g[c] + bb[c] + hv);
}

// ==================================================================================
extern "C" void kernel_launch(void* const* d_in, const int* in_sizes, int n_in,
                              void* d_out, int out_size, void* d_ws, size_t ws_size,
                              hipStream_t stream)
{
  const float* in_x       = (const float*)d_in[0];
  const float* conv_in_w  = (const float*)d_in[1];
  const float* conv_in_b  = (const float*)d_in[2];
  const float* norm_w     = (const float*)d_in[3];
  const float* in_proj_w  = (const float*)d_in[4];
  const float* dwconv_w   = (const float*)d_in[5];
  const float* dwconv_b   = (const float*)d_in[6];
  const float* x_proj_w   = (const float*)d_in[7];
  const float* dt_proj_w  = (const float*)d_in[8];
  const float* dt_proj_b  = (const float*)d_in[9];
  const float* A_log      = (const float*)d_in[10];
  const float* Dvec       = (const float*)d_in[11];
  const float* out_proj_w = (const float*)d_in[12];
  const float* merge_w    = (const float*)d_in[13];
  const float* merge_b    = (const float*)d_in[14];
  const float* bn_g       = (const float*)d_in[15];
  const float* bn_b       = (const float*)d_in[16];
  const float* up1_w      = (const float*)d_in[17];
  const float* up1_b      = (const float*)d_in[18];
  const float* up2_w      = (const float*)d_in[19];
  const float* up2_b      = (const float*)d_in[20];
  const float* out_w      = (const float*)d_in[21];
  const float* out_b      = (const float*)d_in[22];
  float* out = (float*)d_out;

  size_t off = 0;
  auto take = [&](size_t bytes) -> void* {
    void* p = (char*)d_ws + off;
    off += (bytes + 255) & ~(size_t)255;
    return p;
  };
  const size_t F_BDMT = (size_t)BB*DM*TT;    // 2,097,152
  const size_t F_BTDI = (size_t)BB*TT*DI;    // 4,194,304
  float* g_h   = (float*)take(F_BDMT*4);         // (B,64,T) fp32 residual hold
  bf16*  g_ht  = (bf16*) take(F_BDMT*2);         // (B,T,64) bf16
  bf16*  g_st  = (bf16*) take(F_BDMT*2);         // mamba out (B,T,64) bf16
  bf16*  g_m2  = (bf16*) take(F_BDMT*2);         // merge conv out
  bf16*  g_mt  = (bf16*) take(F_BDMT*2);         // BN+res out
  float* g_stt = (float*)take(512);
  short* wp_mg = (short*)take((size_t)15*2*4 *512*2);
  short* wp_u1 = (short*)take((size_t)15*2*100*512*2);
  short* wp_u2 = (short*)take((size_t)15*10*16*512*2);
  short* wp_oc = (short*)take((size_t)15*4*1  *512*2);
  short* wp_ip = (short*)take((size_t)1*2*16*512*2);
  short* wp_xp = (short*)take((size_t)1*4*3 *512*2);
  short* wp_op = (short*)take((size_t)1*4*4 *512*2);
  size_t mamba_base = off;
  bf16*  g_xm  = (bf16*) take(F_BTDI*2);
  bf16*  g_z   = (bf16*) take(F_BTDI*2);
  float* g_xcf = (float*)take(F_BTDI*4);
  bf16*  g_xcb = (bf16*) take(F_BTDI*2);
  float* g_xd  = (float*)take((size_t)BB*TT*48*4);
  float* g_dl  = (float*)take(F_BTDI*4);
  float* g_y   = (float*)take(F_BTDI*4);
  float* g_P   = (float*)take((size_t)BB*NCHK*DI*DSN*4);
  float* g_S   = (float*)take((size_t)BB*NCHK*DI*DSN*4);
  float* g_hs  = (float*)take((size_t)BB*NCHK*DI*DSN*4);
  bf16*  g_u10 = (bf16*)((char*)d_ws + mamba_base);   // 80 MB overlays mamba temps
  bf16*  g_u5  = (bf16*)take((size_t)BB*10240*320*2); // 105 MB
  if (off > ws_size) return;

  // ---- packs + stats zero ----
  k_zero<<<1, 256, 0, stream>>>(g_stt, 128);
  k_pack<<<(15*2*4*64+255)/256, 256, 0, stream>>>(merge_w, wp_mg, 64, 64, 4, 2, 15);
  k_pack<<<(15*2*100*64+255)/256, 256, 0, stream>>>(up1_w, wp_u1, 1600, 64, 100, 2, 15);
  k_pack<<<(15*10*16*64+255)/256, 256, 0, stream>>>(up2_w, wp_u2, 256, 320, 16, 10, 15);
  k_pack<<<(15*4*1*64+255)/256, 256, 0, stream>>>(out_w, wp_oc, 12, 128, 1, 4, 15);
  k_pack<<<(1*2*16*64+255)/256, 256, 0, stream>>>(in_proj_w, wp_ip, 256, 64, 16, 2, 1);
  k_pack<<<(1*4*3*64+255)/256, 256, 0, stream>>>(x_proj_w, wp_xp, 36, 128, 3, 4, 1);
  k_pack<<<(1*4*4*64+255)/256, 256, 0, stream>>>(out_proj_w, wp_op, 64, 128, 4, 4, 1);

  // ---- stage 1 ----
  k_conv_in<<<dim3(TT/256, DM, BB), 256, 0, stream>>>(in_x, conv_in_w, conv_in_b, g_h, g_ht);

  // ---- stage 2: mamba ----
  k_inproj_mfma<<<BB*TT/64, 256, 0, stream>>>(g_ht, norm_w, wp_ip, g_xm, g_z);
  k_dwconv<<<BB*TT*DI/256, 256, 0, stream>>>(g_xm, dwconv_w, dwconv_b, g_xcf, g_xcb);
  k_xproj_mfma<<<BB*TT/256, 256, 0, stream>>>(g_xcb, wp_xp, g_xd);
  k_delta<<<BB*TT*DI/256, 256, 0, stream>>>(g_xd, dt_proj_w, dt_proj_b, g_dl);
  k_scan_sum<<<dim3(DI/16, BB, NCHK), 256, 0, stream>>>(g_dl, g_xcf, g_xd, A_log, g_P, g_S);
  k_scan_comb<<<BB*DI*DSN/256, 256, 0, stream>>>(g_P, g_S, g_hs);
  k_scan_out<<<dim3(DI/16, BB, NCHK), 256, 0, stream>>>(g_dl, g_xcf, g_xd, A_log, Dvec, g_hs, g_y);
  k_outproj_mfma<<<BB*TT/256, 256, 0, stream>>>(g_y, g_z, g_ht, wp_op, g_st);

  // ---- stage 3: merge conv + BN + residual ----
  mfma_conv<64,4,1,false,true,0><<<dim3(TT/256, 1, BB), 256, 0, stream>>>(
      g_st, wp_mg, merge_b, g_m2, g_stt, TT, 4);
  k_bnadd2<<<BB*TT*64/256, 256, 0, stream>>>(g_m2, g_stt, bn_g, bn_b, g_h, g_mt);

  // ---- stage 4: up1 (64 -> 1600, shuffle x5) ----
  mfma_conv<64,5,5,true,false,0><<<dim3(TT/256, 20, BB), 256, 0, stream>>>(
      g_mt, wp_u1, up1_b, g_u5, nullptr, TT, 100);

  // ---- stage 5: up2 (320 -> 256, shuffle x2) ----
  mfma_conv<320,4,2,true,false,0><<<dim3(TT*5/256, 4, BB), 256, 0, stream>>>(
      g_u5, wp_u2, up2_b, g_u10, nullptr, TT*5, 16);

  // ---- stage 6: out conv (128 -> 12), fp32 channel-major ----
  mfma_conv<128,1,1,false,false,1><<<dim3(TT*10/256, 1, BB), 256, 0, stream>>>(
      g_u10, wp_oc, out_b, out, nullptr, TT*10, 1);
}